// Round 10
// baseline (1786.129 us; speedup 1.0000x reference)
//
#include <hip/hip_runtime.h>
#include <stdint.h>
#include <stddef.h>

// ---------------------------------------------------------------------------
// GRBM Gibbs sampling, round 10. Schedule-only changes vs R9 (numerics are
// bit-identical: same MFMA sequence & order -> absmax must stay EXACTLY
// 0.1015625; that's the regression canary).
//  - L-mfma: 2-barrier -> 1-barrier dbuf (STAGE p -> LOAD t+1 -> bar -> COMPUTE)
//    (proven +40% on the fp32 L at the same 2 blocks/CU).
//  - V-mfma: KT 32 -> 64 (halves barrier/drain count; 73.7 KB LDS, 2 blk/CU).
// ---------------------------------------------------------------------------

typedef __attribute__((ext_vector_type(8))) __bf16 bf16x8;
typedef __attribute__((ext_vector_type(4))) float f32x4;

__host__ __device__ inline void threefry2x32(uint32_t k0, uint32_t k1,
                                             uint32_t x0, uint32_t x1,
                                             uint32_t& o0, uint32_t& o1) {
  uint32_t ks2 = k0 ^ k1 ^ 0x1BD11BDAu;
  x0 += k0; x1 += k1;
#define TFR(r) { x0 += x1; x1 = (x1 << (r)) | (x1 >> (32 - (r))); x1 ^= x0; }
  TFR(13) TFR(15) TFR(26) TFR(6)
  x0 += k1;  x1 += ks2 + 1u;
  TFR(17) TFR(29) TFR(16) TFR(24)
  x0 += ks2; x1 += k0 + 2u;
  TFR(13) TFR(15) TFR(26) TFR(6)
  x0 += k0;  x1 += k1 + 3u;
  TFR(17) TFR(29) TFR(16) TFR(24)
  x0 += k1;  x1 += ks2 + 4u;
  TFR(13) TFR(15) TFR(26) TFR(6)
  x0 += ks2; x1 += k0 + 5u;
#undef TFR
  o0 = x0; o1 = x1;
}

__device__ inline float jax_uniform01(uint32_t key0, uint32_t key1, uint32_t idx) {
  uint32_t o0, o1;
  threefry2x32(key0, key1, 0u, idx, o0, o1);
  uint32_t bits = o0 ^ o1;
  return __uint_as_float((bits >> 9) | 0x3f800000u) - 1.0f;
}

__device__ inline float erfinv_xla(float x) {
  float w = -log1pf(-x * x);
  float p;
  if (w < 5.0f) {
    w = w - 2.5f;
    p = 2.81022636e-08f;
    p = fmaf(p, w, 3.43273939e-07f);
    p = fmaf(p, w, -3.5233877e-06f);
    p = fmaf(p, w, -4.39150654e-06f);
    p = fmaf(p, w, 0.00021858087f);
    p = fmaf(p, w, -0.00125372503f);
    p = fmaf(p, w, -0.00417768164f);
    p = fmaf(p, w, 0.246640727f);
    p = fmaf(p, w, 1.50140941f);
  } else {
    w = sqrtf(w) - 3.0f;
    p = -0.000200214257f;
    p = fmaf(p, w, 0.000100950558f);
    p = fmaf(p, w, 0.00134934322f);
    p = fmaf(p, w, -0.00367342844f);
    p = fmaf(p, w, 0.00573950773f);
    p = fmaf(p, w, -0.0076224613f);
    p = fmaf(p, w, 0.00943887047f);
    p = fmaf(p, w, 1.00167406f);
    p = fmaf(p, w, 2.83297682f);
  }
  return p * x;
}

__global__ void prep_kernel(const float* __restrict__ log_var,
                            float* __restrict__ invvar,
                            float* __restrict__ stdv, int V) {
  int i = blockIdx.x * 256 + threadIdx.x;
  if (i < V) {
    float var = fmaxf(expf(log_var[i]), 1e-8f);
    invvar[i] = 1.0f / var;
    stdv[i] = sqrtf(var);
  }
}

__device__ inline unsigned short rtn_bf16(float x, float& back) {
  uint32_t u = __float_as_uint(x);
  uint32_t r = u + 0x7fffu + ((u >> 16) & 1u);
  unsigned short s = (unsigned short)(r >> 16);
  back = __uint_as_float(((uint32_t)s) << 16);
  return s;
}

__device__ inline void split3(float x, unsigned short& s0, unsigned short& s1,
                              unsigned short& s2) {
  float b, r1, r2;
  s0 = rtn_bf16(x, b);  r1 = x - b;
  s1 = rtn_bf16(r1, b); r2 = r1 - b;
  s2 = rtn_bf16(r2, b);
}

__global__ __launch_bounds__(256)
void split_w_kernel(const float* __restrict__ W,
                    unsigned short* __restrict__ P0,
                    unsigned short* __restrict__ P1,
                    unsigned short* __restrict__ P2) {
  int gid = blockIdx.x * 256 + threadIdx.x;
  int base = gid * 4;
  float4 x = *reinterpret_cast<const float4*>(&W[base]);
  ushort4 a0, a1, a2;
  split3(x.x, a0.x, a1.x, a2.x);
  split3(x.y, a0.y, a1.y, a2.y);
  split3(x.z, a0.z, a1.z, a2.z);
  split3(x.w, a0.w, a1.w, a2.w);
  *reinterpret_cast<ushort4*>(&P0[base]) = a0;
  *reinterpret_cast<ushort4*>(&P1[base]) = a1;
  *reinterpret_cast<ushort4*>(&P2[base]) = a2;
}

__global__ __launch_bounds__(256)
void split_wl_kernel(const float* __restrict__ W, const float* __restrict__ invvar,
                     unsigned short* __restrict__ T0,
                     unsigned short* __restrict__ T1,
                     unsigned short* __restrict__ T2) {
  const int N = 512, K = 3072;
  const int n = blockIdx.x * 64 + (threadIdx.x & 63);
  const int kb = blockIdx.y * 16 + (threadIdx.x >> 6) * 4;
  ushort4 a0, a1, a2;
  {
    float w0 = W[(size_t)(kb + 0) * N + n] * invvar[kb + 0];
    float w1 = W[(size_t)(kb + 1) * N + n] * invvar[kb + 1];
    float w2 = W[(size_t)(kb + 2) * N + n] * invvar[kb + 2];
    float w3 = W[(size_t)(kb + 3) * N + n] * invvar[kb + 3];
    split3(w0, a0.x, a1.x, a2.x);
    split3(w1, a0.y, a1.y, a2.y);
    split3(w2, a0.z, a1.z, a2.z);
    split3(w3, a0.w, a1.w, a2.w);
  }
  size_t o = (size_t)n * K + kb;
  *reinterpret_cast<ushort4*>(&T0[o]) = a0;
  *reinterpret_cast<ushort4*>(&T1[o]) = a1;
  *reinterpret_cast<ushort4*>(&T2[o]) = a2;
}

__global__ __launch_bounds__(256)
void split_a_kernel(const float* __restrict__ Vin,
                    unsigned short* __restrict__ A0,
                    unsigned short* __restrict__ A1,
                    unsigned short* __restrict__ A2) {
  int gid = blockIdx.x * 256 + threadIdx.x;
  int base = gid * 4;
  float4 x = *reinterpret_cast<const float4*>(&Vin[base]);
  ushort4 a0, a1, a2;
  split3(x.x, a0.x, a1.x, a2.x);
  split3(x.y, a0.y, a1.y, a2.y);
  split3(x.z, a0.z, a1.z, a2.z);
  split3(x.w, a0.w, a1.w, a2.w);
  *reinterpret_cast<ushort4*>(&A0[base]) = a0;
  *reinterpret_cast<ushort4*>(&A1[base]) = a1;
  *reinterpret_cast<ushort4*>(&A2[base]) = a2;
}

// ---------------------------------------------------------------------------
// Kernel L-MFMA (1-barrier dbuf): logits = v @ (ivv*W) + b ; h = bern(sigmoid).
// M=4096, N=512, K=3072. BM=BN=64, 4 waves (2x2 of 32x32), KT=32.
// 6 pruned passes. grid=512 XCD-swizzled, 2 blocks/CU.
// ---------------------------------------------------------------------------
__global__ __launch_bounds__(256, 1)
void gemm_logit_mfma(const unsigned short* __restrict__ A0,
                     const unsigned short* __restrict__ A1,
                     const unsigned short* __restrict__ A2,
                     const unsigned short* __restrict__ T0,
                     const unsigned short* __restrict__ T1,
                     const unsigned short* __restrict__ T2,
                     const float* __restrict__ bias,
                     uint8_t* __restrict__ Hout, uint32_t kb0, uint32_t kb1) {
  const int N = 512, K = 3072;
  __shared__ __attribute__((aligned(16))) unsigned short As[2][3][64][40];
  __shared__ __attribute__((aligned(16))) unsigned short Bs[2][3][64][40];

  const int tid = threadIdx.x;
  const int bid = blockIdx.x;
  const int xcd = bid & 7;
  const int c = bid >> 3;
  const int mb = xcd * 8 + (c >> 3);     // 0..63
  const int nb = c & 7;                  // 0..7
  const int mBase = mb * 64, nBase = nb * 64;

  const int lane = tid & 63, w = tid >> 6;
  const int wr = w >> 1, wc = w & 1;
  const int lg = lane >> 4, lm = lane & 15;

  const int srow = tid >> 2;        // 0..63
  const int soff = (tid & 3) * 8;   // 0,8,16,24

  f32x4 acc00 = {0.f, 0.f, 0.f, 0.f};
  f32x4 acc01 = {0.f, 0.f, 0.f, 0.f};
  f32x4 acc10 = {0.f, 0.f, 0.f, 0.f};
  f32x4 acc11 = {0.f, 0.f, 0.f, 0.f};

  bf16x8 ra0, ra1, ra2, rb0, rb1, rb2;

#define LOADL(t) { \
  size_t ao = (size_t)(mBase + srow) * K + (t) * 32 + soff; \
  size_t bo = (size_t)(nBase + srow) * K + (t) * 32 + soff; \
  ra0 = *reinterpret_cast<const bf16x8*>(&A0[ao]); \
  ra1 = *reinterpret_cast<const bf16x8*>(&A1[ao]); \
  ra2 = *reinterpret_cast<const bf16x8*>(&A2[ao]); \
  rb0 = *reinterpret_cast<const bf16x8*>(&T0[bo]); \
  rb1 = *reinterpret_cast<const bf16x8*>(&T1[bo]); \
  rb2 = *reinterpret_cast<const bf16x8*>(&T2[bo]); }

#define STAGEL(p) { \
  *reinterpret_cast<bf16x8*>(&As[p][0][srow][soff]) = ra0; \
  *reinterpret_cast<bf16x8*>(&As[p][1][srow][soff]) = ra1; \
  *reinterpret_cast<bf16x8*>(&As[p][2][srow][soff]) = ra2; \
  *reinterpret_cast<bf16x8*>(&Bs[p][0][srow][soff]) = rb0; \
  *reinterpret_cast<bf16x8*>(&Bs[p][1][srow][soff]) = rb1; \
  *reinterpret_cast<bf16x8*>(&Bs[p][2][srow][soff]) = rb2; }

  LOADL(0)

  int p = 0;
  const int NT = K / 32;   // 96
  for (int t = 0; t < NT; ++t) {
    STAGEL(p)
    if (t + 1 < NT) LOADL(t + 1)
    __syncthreads();

    bf16x8 a00 = *reinterpret_cast<const bf16x8*>(&As[p][0][wr * 32 + lm][lg * 8]);
    bf16x8 a01 = *reinterpret_cast<const bf16x8*>(&As[p][0][wr * 32 + 16 + lm][lg * 8]);
    bf16x8 a10 = *reinterpret_cast<const bf16x8*>(&As[p][1][wr * 32 + lm][lg * 8]);
    bf16x8 a11 = *reinterpret_cast<const bf16x8*>(&As[p][1][wr * 32 + 16 + lm][lg * 8]);
    bf16x8 a20 = *reinterpret_cast<const bf16x8*>(&As[p][2][wr * 32 + lm][lg * 8]);
    bf16x8 a21 = *reinterpret_cast<const bf16x8*>(&As[p][2][wr * 32 + 16 + lm][lg * 8]);
    bf16x8 b00 = *reinterpret_cast<const bf16x8*>(&Bs[p][0][wc * 32 + lm][lg * 8]);
    bf16x8 b01 = *reinterpret_cast<const bf16x8*>(&Bs[p][0][wc * 32 + 16 + lm][lg * 8]);
    bf16x8 b10 = *reinterpret_cast<const bf16x8*>(&Bs[p][1][wc * 32 + lm][lg * 8]);
    bf16x8 b11 = *reinterpret_cast<const bf16x8*>(&Bs[p][1][wc * 32 + 16 + lm][lg * 8]);
    bf16x8 b20 = *reinterpret_cast<const bf16x8*>(&Bs[p][2][wc * 32 + lm][lg * 8]);
    bf16x8 b21 = *reinterpret_cast<const bf16x8*>(&Bs[p][2][wc * 32 + 16 + lm][lg * 8]);

#define PASS(aa0, aa1, bb0, bb1) \
    acc00 = __builtin_amdgcn_mfma_f32_16x16x32_bf16(aa0, bb0, acc00, 0, 0, 0); \
    acc01 = __builtin_amdgcn_mfma_f32_16x16x32_bf16(aa0, bb1, acc01, 0, 0, 0); \
    acc10 = __builtin_amdgcn_mfma_f32_16x16x32_bf16(aa1, bb0, acc10, 0, 0, 0); \
    acc11 = __builtin_amdgcn_mfma_f32_16x16x32_bf16(aa1, bb1, acc11, 0, 0, 0);

    PASS(a00, a01, b00, b01)   // A0*B0
    PASS(a00, a01, b10, b11)   // A0*B1
    PASS(a10, a11, b00, b01)   // A1*B0
    PASS(a00, a01, b20, b21)   // A0*B2
    PASS(a10, a11, b10, b11)   // A1*B1
    PASS(a20, a21, b00, b01)   // A2*B0
#undef PASS

    p ^= 1;
  }
#undef LOADL
#undef STAGEL

  const int col0 = nBase + wc * 32 + lm;
  const int col1 = col0 + 16;
  const float bias0 = bias[col0], bias1 = bias[col1];

#define HOUT(accv, r, rowv, colv, bv) { \
  int row = (rowv); int col = (colv); \
  float logit = accv[r] + (bv); \
  float p2 = 0.5f + 0.5f * tanhf(0.5f * logit); \
  uint32_t idx = (uint32_t)row * (uint32_t)N + (uint32_t)col; \
  float u = jax_uniform01(kb0, kb1, idx); \
  Hout[(size_t)row * N + col] = (u < p2) ? (uint8_t)1 : (uint8_t)0; }

#pragma unroll
  for (int r = 0; r < 4; ++r) {
    int row0 = mBase + wr * 32 + lg * 4 + r;
    int row1 = row0 + 16;
    HOUT(acc00, r, row0, col0, bias0)
    HOUT(acc01, r, row0, col1, bias1)
    HOUT(acc10, r, row1, col0, bias0)
    HOUT(acc11, r, row1, col1, bias1)
  }
#undef HOUT
}

// ---------------------------------------------------------------------------
// Kernel V-MFMA (KT=64, 2-barrier dbuf): v = h@W^T + mu + nz*std.
// M=4096, N=3072, K=512. BM=BN=64, 4 waves. 8 K-tiles. LDS 73.7 KB, 2 blk/CU.
// MFMA order per 64-k tile = two successive 32-k subtiles in the old order
// -> bit-identical accumulation vs R9.
// ---------------------------------------------------------------------------
__global__ __launch_bounds__(256, 1)
void gemm_v_mfma(const uint8_t* __restrict__ Hin,
                 const unsigned short* __restrict__ W0,
                 const unsigned short* __restrict__ W1,
                 const unsigned short* __restrict__ W2,
                 const float* __restrict__ muv, const float* __restrict__ stdv,
                 float* __restrict__ Vout,
                 unsigned short* __restrict__ A0,
                 unsigned short* __restrict__ A1,
                 unsigned short* __restrict__ A2,
                 uint32_t kn0, uint32_t kn1) {
  const int N = 3072, K = 512;
  __shared__ __attribute__((aligned(16))) unsigned short As[2][64][72];
  __shared__ __attribute__((aligned(16))) unsigned short Bs[2][3][64][72];

  const int tid = threadIdx.x;
  const int mBase = blockIdx.y * 64, nBase = blockIdx.x * 64;
  const int lane = tid & 63, w = tid >> 6;
  const int wr = w >> 1, wc = w & 1;
  const int lg = lane >> 4, lm = lane & 15;

  const int srow = tid >> 2;        // 0..63
  const int soff = (tid & 3) * 8;   // 0,8,16,24 (+32 for hi half)

  f32x4 acc00 = {0.f, 0.f, 0.f, 0.f};
  f32x4 acc01 = {0.f, 0.f, 0.f, 0.f};
  f32x4 acc10 = {0.f, 0.f, 0.f, 0.f};
  f32x4 acc11 = {0.f, 0.f, 0.f, 0.f};

  const __bf16 ONE = (__bf16)1.0f;
  const __bf16 ZERO = (__bf16)0.0f;

  uint64_t rha, rhb;
  bf16x8 rw0a, rw0b, rw1a, rw1b, rw2a, rw2b;

#define LOADV(t) { \
  size_t ho = (size_t)(mBase + srow) * K + (t) * 64 + soff; \
  size_t wo = (size_t)(nBase + srow) * K + (t) * 64 + soff; \
  rha  = *reinterpret_cast<const uint64_t*>(&Hin[ho]); \
  rhb  = *reinterpret_cast<const uint64_t*>(&Hin[ho + 32]); \
  rw0a = *reinterpret_cast<const bf16x8*>(&W0[wo]); \
  rw0b = *reinterpret_cast<const bf16x8*>(&W0[wo + 32]); \
  rw1a = *reinterpret_cast<const bf16x8*>(&W1[wo]); \
  rw1b = *reinterpret_cast<const bf16x8*>(&W1[wo + 32]); \
  rw2a = *reinterpret_cast<const bf16x8*>(&W2[wo]); \
  rw2b = *reinterpret_cast<const bf16x8*>(&W2[wo + 32]); }

#define HEXP(dst, rh) { \
  dst[0] = ((rh >> 0)  & 0xffu) ? ONE : ZERO; \
  dst[1] = ((rh >> 8)  & 0xffu) ? ONE : ZERO; \
  dst[2] = ((rh >> 16) & 0xffu) ? ONE : ZERO; \
  dst[3] = ((rh >> 24) & 0xffu) ? ONE : ZERO; \
  dst[4] = ((rh >> 32) & 0xffu) ? ONE : ZERO; \
  dst[5] = ((rh >> 40) & 0xffu) ? ONE : ZERO; \
  dst[6] = ((rh >> 48) & 0xffu) ? ONE : ZERO; \
  dst[7] = ((rh >> 56) & 0xffu) ? ONE : ZERO; }

#define STAGEV(p) { \
  bf16x8 hva, hvb; \
  HEXP(hva, rha) \
  HEXP(hvb, rhb) \
  *reinterpret_cast<bf16x8*>(&As[p][srow][soff])         = hva; \
  *reinterpret_cast<bf16x8*>(&As[p][srow][soff + 32])    = hvb; \
  *reinterpret_cast<bf16x8*>(&Bs[p][0][srow][soff])      = rw0a; \
  *reinterpret_cast<bf16x8*>(&Bs[p][0][srow][soff + 32]) = rw0b; \
  *reinterpret_cast<bf16x8*>(&Bs[p][1][srow][soff])      = rw1a; \
  *reinterpret_cast<bf16x8*>(&Bs[p][1][srow][soff + 32]) = rw1b; \
  *reinterpret_cast<bf16x8*>(&Bs[p][2][srow][soff])      = rw2a; \
  *reinterpret_cast<bf16x8*>(&Bs[p][2][srow][soff + 32]) = rw2b; }

  LOADV(0)
  STAGEV(0)
  __syncthreads();

  int cur = 0;
  const int NT = K / 64;   // 8
  for (int t = 0; t < NT; ++t) {
    const bool more = (t + 1 < NT);
    if (more) LOADV(t + 1)

#pragma unroll
    for (int ks = 0; ks < 2; ++ks) {
      const int ko = ks * 32 + lg * 8;
      bf16x8 a0 = *reinterpret_cast<const bf16x8*>(&As[cur][wr * 32 + lm][ko]);
      bf16x8 a1 = *reinterpret_cast<const bf16x8*>(&As[cur][wr * 32 + 16 + lm][ko]);
      bf16x8 b00 = *reinterpret_cast<const bf16x8*>(&Bs[cur][0][wc * 32 + lm][ko]);
      bf16x8 b01 = *reinterpret_cast<const bf16x8*>(&Bs[cur][0][wc * 32 + 16 + lm][ko]);
      bf16x8 b10 = *reinterpret_cast<const bf16x8*>(&Bs[cur][1][wc * 32 + lm][ko]);
      bf16x8 b11 = *reinterpret_cast<const bf16x8*>(&Bs[cur][1][wc * 32 + 16 + lm][ko]);
      bf16x8 b20 = *reinterpret_cast<const bf16x8*>(&Bs[cur][2][wc * 32 + lm][ko]);
      bf16x8 b21 = *reinterpret_cast<const bf16x8*>(&Bs[cur][2][wc * 32 + 16 + lm][ko]);

      acc00 = __builtin_amdgcn_mfma_f32_16x16x32_bf16(a0, b00, acc00, 0, 0, 0);
      acc01 = __builtin_amdgcn_mfma_f32_16x16x32_bf16(a0, b01, acc01, 0, 0, 0);
      acc10 = __builtin_amdgcn_mfma_f32_16x16x32_bf16(a1, b00, acc10, 0, 0, 0);
      acc11 = __builtin_amdgcn_mfma_f32_16x16x32_bf16(a1, b01, acc11, 0, 0, 0);
      acc00 = __builtin_amdgcn_mfma_f32_16x16x32_bf16(a0, b10, acc00, 0, 0, 0);
      acc01 = __builtin_amdgcn_mfma_f32_16x16x32_bf16(a0, b11, acc01, 0, 0, 0);
      acc10 = __builtin_amdgcn_mfma_f32_16x16x32_bf16(a1, b10, acc10, 0, 0, 0);
      acc11 = __builtin_amdgcn_mfma_f32_16x16x32_bf16(a1, b11, acc11, 0, 0, 0);
      acc00 = __builtin_amdgcn_mfma_f32_16x16x32_bf16(a0, b20, acc00, 0, 0, 0);
      acc01 = __builtin_amdgcn_mfma_f32_16x16x32_bf16(a0, b21, acc01, 0, 0, 0);
      acc10 = __builtin_amdgcn_mfma_f32_16x16x32_bf16(a1, b20, acc10, 0, 0, 0);
      acc11 = __builtin_amdgcn_mfma_f32_16x16x32_bf16(a1, b21, acc11, 0, 0, 0);
    }

    if (more) {
      __syncthreads();
      STAGEV(cur ^ 1)
      __syncthreads();
      cur ^= 1;
    }
  }
#undef LOADV
#undef STAGEV
#undef HEXP

  const float LO = -0.99999994f;
  const float SQRT2 = 1.41421356237f;
  const int col0 = nBase + wc * 32 + lm;
  const int col1 = col0 + 16;
  const float mu0 = muv[col0], mu1 = muv[col1];
  const float sd0 = stdv[col0], sd1 = stdv[col1];
  const bool emitA = (A0 != nullptr);

#define VOUTM(accv, r, rowv, colv, muvv, sdvv) { \
  int row = (rowv); int col = (colv); \
  float m_v = accv[r] + (muvv); \
  uint32_t idx = (uint32_t)row * (uint32_t)N + (uint32_t)col; \
  float f = jax_uniform01(kn0, kn1, idx); \
  float u = fmaxf(LO, fmaf(f, 2.0f, LO)); \
  float nz = SQRT2 * erfinv_xla(u); \
  float vv = m_v + nz * (sdvv); \
  Vout[(size_t)row * N + col] = vv; \
  if (emitA) { \
    unsigned short s0, s1, s2; \
    split3(vv, s0, s1, s2); \
    size_t ao = (size_t)row * N + col; \
    A0[ao] = s0; A1[ao] = s1; A2[ao] = s2; \
  } }

#pragma unroll
  for (int r = 0; r < 4; ++r) {
    int row0 = mBase + wr * 32 + lg * 4 + r;
    int row1 = row0 + 16;
    VOUTM(acc00, r, row0, col0, mu0, sd0)
    VOUTM(acc01, r, row0, col1, mu1, sd1)
    VOUTM(acc10, r, row1, col0, mu0, sd0)
    VOUTM(acc11, r, row1, col1, mu1, sd1)
  }
#undef VOUTM
}

// ---------------------------------------------------------------------------
// Fallback fp32 kernels (R7-proven) — used when ws_size is too small.
// ---------------------------------------------------------------------------
__global__ __launch_bounds__(256, 1)
void gemm_logit_bern(const float* __restrict__ Vin, const float* __restrict__ Wm,
                     const float* __restrict__ bias, const float* __restrict__ invvar,
                     uint8_t* __restrict__ Hout, uint32_t kb0, uint32_t kb1) {
  const int N = 512, K = 3072;
  const int KT = 32;
  __shared__ float As[2][KT][68];
  __shared__ float Bs[2][KT][64];

  const int tid = threadIdx.x;
  const int bid = blockIdx.x;
  const int xcd = bid & 7;
  const int c = bid >> 3;
  const int mb = xcd * 8 + (c >> 3);
  const int nb = c & 7;
  const int mBase = mb * 64, nBase = nb * 64;

  const int tx = tid & 15, ty = tid >> 4;
  const int am = tid >> 2;
  const int ak = (tid & 3) * 4;
  const int bk = tid >> 4;
  const int bn = (tid & 15) * 4;

  float acc[4][4] = {};
  float4 ra0, ra1, riv0, riv1, rb0, rb1;

#define LOADL(t) { \
  int k0 = (t) * KT; \
  ra0  = *reinterpret_cast<const float4*>(&Vin[(size_t)(mBase + am) * K + k0 + ak]); \
  ra1  = *reinterpret_cast<const float4*>(&Vin[(size_t)(mBase + am) * K + k0 + 16 + ak]); \
  riv0 = *reinterpret_cast<const float4*>(&invvar[k0 + ak]); \
  riv1 = *reinterpret_cast<const float4*>(&invvar[k0 + 16 + ak]); \
  rb0  = *reinterpret_cast<const float4*>(&Wm[(size_t)(k0 + bk) * N + nBase + bn]); \
  rb1  = *reinterpret_cast<const float4*>(&Wm[(size_t)(k0 + 16 + bk) * N + nBase + bn]); }

#define STOREL(p) { \
  As[p][ak + 0][am]      = ra0.x * riv0.x; \
  As[p][ak + 1][am]      = ra0.y * riv0.y; \
  As[p][ak + 2][am]      = ra0.z * riv0.z; \
  As[p][ak + 3][am]      = ra0.w * riv0.w; \
  As[p][ak + 16][am]     = ra1.x * riv1.x; \
  As[p][ak + 17][am]     = ra1.y * riv1.y; \
  As[p][ak + 18][am]     = ra1.z * riv1.z; \
  As[p][ak + 19][am]     = ra1.w * riv1.w; \
  *reinterpret_cast<float4*>(&Bs[p][bk][bn])      = rb0; \
  *reinterpret_cast<float4*>(&Bs[p][bk + 16][bn]) = rb1; }

  LOADL(0)
  int p = 0;
  const int NT = K / KT;
  for (int t = 0; t < NT; ++t) {
    STOREL(p)
    if (t + 1 < NT) LOADL(t + 1)
    __syncthreads();
#pragma unroll
    for (int kk = 0; kk < KT; ++kk) {
      float4 x = *reinterpret_cast<const float4*>(&As[p][kk][ty * 4]);
      float4 y = *reinterpret_cast<const float4*>(&Bs[p][kk][tx * 4]);
#define LROW(i, a) \
      acc[i][0] = fmaf(a, y.x, acc[i][0]); \
      acc[i][1] = fmaf(a, y.y, acc[i][1]); \
      acc[i][2] = fmaf(a, y.z, acc[i][2]); \
      acc[i][3] = fmaf(a, y.w, acc[i][3]);
      LROW(0, x.x) LROW(1, x.y) LROW(2, x.z) LROW(3, x.w)
#undef LROW
    }
    p ^= 1;
  }
#undef LOADL
#undef STOREL

#pragma unroll
  for (int i = 0; i < 4; ++i) {
    int row = mBase + ty * 4 + i;
    uint32_t hp = 0;
#pragma unroll
    for (int j = 0; j < 4; ++j) {
      int col = nBase + tx * 4 + j;
      float logit = acc[i][j] + bias[col];
      float p2 = 0.5f + 0.5f * tanhf(0.5f * logit);
      uint32_t idx = (uint32_t)row * (uint32_t)N + (uint32_t)col;
      float u = jax_uniform01(kb0, kb1, idx);
      hp |= ((u < p2) ? 1u : 0u) << (8 * j);
    }
    *reinterpret_cast<uint32_t*>(&Hout[(size_t)row * N + nBase + tx * 4]) = hp;
  }
}

__global__ __launch_bounds__(256, 2)
void gemm_v_sample(const uint8_t* __restrict__ Hin, const float* __restrict__ Wm,
                   const float* __restrict__ muv, const float* __restrict__ stdv,
                   float* __restrict__ Vout, uint32_t kn0, uint32_t kn1) {
  const int N = 3072, K = 512;
  const int KT = 16;
  __shared__ float As[2][KT][132];
  __shared__ float Bs[2][KT][68];

  const int tid = threadIdx.x;
  const int mBase = blockIdx.y * 128, nBase = blockIdx.x * 64;
  const int tx = tid & 15, ty = tid >> 4;
  const int am = tid >> 1;
  const int ah = (tid & 1) * 8;
  const int bn = tid >> 2;
  const int bq = (tid & 3) * 4;

  float acc[8][4] = {};
  uint32_t rh0, rh1;
  float4 rb;
  {
    const uint32_t* hp_ = reinterpret_cast<const uint32_t*>(&Hin[(size_t)(mBase + am) * K + ah]);
    rh0 = hp_[0]; rh1 = hp_[1];
  }
  rb = *reinterpret_cast<const float4*>(&Wm[(size_t)(nBase + bn) * K + bq]);

#define STAGE_V(buf) { \
  As[buf][ah + 0][am] = (float)((rh0 >> 0) & 0xffu); \
  As[buf][ah + 1][am] = (float)((rh0 >> 8) & 0xffu); \
  As[buf][ah + 2][am] = (float)((rh0 >> 16) & 0xffu); \
  As[buf][ah + 3][am] = (float)((rh0 >> 24) & 0xffu); \
  As[buf][ah + 4][am] = (float)((rh1 >> 0) & 0xffu); \
  As[buf][ah + 5][am] = (float)((rh1 >> 8) & 0xffu); \
  As[buf][ah + 6][am] = (float)((rh1 >> 16) & 0xffu); \
  As[buf][ah + 7][am] = (float)((rh1 >> 24) & 0xffu); \
  Bs[buf][bq + 0][bn] = rb.x; \
  Bs[buf][bq + 1][bn] = rb.y; \
  Bs[buf][bq + 2][bn] = rb.z; \
  Bs[buf][bq + 3][bn] = rb.w; }

  STAGE_V(0)
  __syncthreads();

  int cur = 0;
  const int NT = K / KT;
  for (int t = 0; t < NT; ++t) {
    const bool more = (t + 1 < NT);
    if (more) {
      int k0 = (t + 1) * KT;
      const uint32_t* hp_ = reinterpret_cast<const uint32_t*>(&Hin[(size_t)(mBase + am) * K + k0 + ah]);
      rh0 = hp_[0]; rh1 = hp_[1];
      rb = *reinterpret_cast<const float4*>(&Wm[(size_t)(nBase + bn) * K + k0 + bq]);
    }
#pragma unroll
    for (int kk = 0; kk < KT; ++kk) {
      float4 x0 = *reinterpret_cast<const float4*>(&As[cur][kk][ty * 8]);
      float4 x1 = *reinterpret_cast<const float4*>(&As[cur][kk][ty * 8 + 4]);
      float4 y  = *reinterpret_cast<const float4*>(&Bs[cur][kk][tx * 4]);
#define VROW(i, a) \
      acc[i][0] = fmaf(a, y.x, acc[i][0]); \
      acc[i][1] = fmaf(a, y.y, acc[i][1]); \
      acc[i][2] = fmaf(a, y.z, acc[i][2]); \
      acc[i][3] = fmaf(a, y.w, acc[i][3]);
      VROW(0, x0.x) VROW(1, x0.y) VROW(2, x0.z) VROW(3, x0.w)
      VROW(4, x1.x) VROW(5, x1.y) VROW(6, x1.z) VROW(7, x1.w)
#undef VROW
    }
    if (more) {
      __syncthreads();
      STAGE_V(cur ^ 1)
      __syncthreads();
      cur ^= 1;
    }
  }
#undef STAGE_V

  const float LO = -0.99999994f;
  const float SQRT2 = 1.41421356237f;
  const float4 mu4 = *reinterpret_cast<const float4*>(&muv[nBase + tx * 4]);
  const float4 sd4 = *reinterpret_cast<const float4*>(&stdv[nBase + tx * 4]);
  const float mur[4] = {mu4.x, mu4.y, mu4.z, mu4.w};
  const float sdr[4] = {sd4.x, sd4.y, sd4.z, sd4.w};
#pragma unroll
  for (int i = 0; i < 8; ++i) {
    int row = mBase + ty * 8 + i;
    float o0, o1, o2, o3;
#define VOUT(j, dst) { \
      int col = nBase + tx * 4 + j; \
      float m_v = acc[i][j] + mur[j]; \
      uint32_t idx = (uint32_t)row * (uint32_t)N + (uint32_t)col; \
      float f = jax_uniform01(kn0, kn1, idx); \
      float u = fmaxf(LO, fmaf(f, 2.0f, LO)); \
      float nz = SQRT2 * erfinv_xla(u); \
      dst = m_v + nz * sdr[j]; }
    VOUT(0, o0) VOUT(1, o1) VOUT(2, o2) VOUT(3, o3)
#undef VOUT
    float4 s = {o0, o1, o2, o3};
    *reinterpret_cast<float4*>(&Vout[(size_t)row * N + nBase + tx * 4]) = s;
  }
}

extern "C" void kernel_launch(void* const* d_in, const int* in_sizes, int n_in,
                              void* d_out, int out_size, void* d_ws, size_t ws_size,
                              hipStream_t stream) {
  const int B = 4096, V = 3072, H = 512, NUM_STEPS = 8;
  const float* v_in    = (const float*)d_in[0];
  const float* W       = (const float*)d_in[1];
  const float* b       = (const float*)d_in[2];
  const float* mu      = (const float*)d_in[3];
  const float* log_var = (const float*)d_in[4];
  float* out = (float*)d_out;

  const size_t WELEMS = (size_t)V * H;           // 1,572,864
  const size_t AELEMS = (size_t)B * V;           // 12,582,912
  const size_t NEED_FULL = 24576 + 6 * WELEMS * 2 + 3 * AELEMS * 2 + (size_t)B * H;
  const size_t NEED_MID  = 24576 + 3 * WELEMS * 2 + (size_t)B * H;
  const int mode = (ws_size >= NEED_FULL) ? 2 : (ws_size >= NEED_MID) ? 1 : 0;

  float* invvar = (float*)d_ws;
  float* stdv   = invvar + V;
  unsigned short* WV0 = (unsigned short*)(stdv + V);
  unsigned short* WV1 = WV0 + WELEMS;
  unsigned short* WV2 = WV1 + WELEMS;
  unsigned short* WT0 = WV2 + WELEMS;
  unsigned short* WT1 = WT0 + WELEMS;
  unsigned short* WT2 = WT1 + WELEMS;
  unsigned short* A0  = WT2 + WELEMS;
  unsigned short* A1  = A0 + AELEMS;
  unsigned short* A2  = A1 + AELEMS;
  uint8_t* h;
  if (mode == 2)      h = (uint8_t*)(A2 + AELEMS);
  else if (mode == 1) h = (uint8_t*)(WV2 + WELEMS);
  else                h = (uint8_t*)(stdv + V);

  uint32_t k0a, k0b, kl0, kl1;
  threefry2x32(0u, 42u, 0u, 0u, k0a, k0b);
  threefry2x32(0u, 42u, 0u, 1u, kl0, kl1);
  uint32_t kn0[NUM_STEPS], kn1[NUM_STEPS], kb0[NUM_STEPS], kb1[NUM_STEPS];
  for (int t = 0; t < NUM_STEPS; ++t) {
    uint32_t kt0, kt1;
    threefry2x32(kl0, kl1, 0u, (uint32_t)t, kt0, kt1);
    threefry2x32(kt0, kt1, 0u, 0u, kn0[t], kn1[t]);
    threefry2x32(kt0, kt1, 0u, 1u, kb0[t], kb1[t]);
  }

  prep_kernel<<<(V + 255) / 256, 256, 0, stream>>>(log_var, invvar, stdv, V);

  dim3 gridL32(512);
  dim3 gridLm(512);
  dim3 gridVm(V / 64, B / 64);     // (48, 64)
  dim3 gridVf(V / 64, B / 128);

  if (mode == 2) {
    split_w_kernel<<<(int)(WELEMS / 4 / 256), 256, 0, stream>>>(W, WV0, WV1, WV2);
    split_wl_kernel<<<dim3(H / 64, V / 16), 256, 0, stream>>>(W, invvar, WT0, WT1, WT2);
    split_a_kernel<<<(int)(AELEMS / 4 / 256), 256, 0, stream>>>(v_in, A0, A1, A2);

    gemm_logit_mfma<<<gridLm, 256, 0, stream>>>(A0, A1, A2, WT0, WT1, WT2, b, h, k0a, k0b);
    for (int t = 0; t < NUM_STEPS; ++t) {
      float* vt = out + (size_t)t * B * V;
      gemm_v_mfma<<<gridVm, 256, 0, stream>>>(h, WV0, WV1, WV2, mu, stdv, vt,
                                              A0, A1, A2, kn0[t], kn1[t]);
      if (t < NUM_STEPS - 1) {
        gemm_logit_mfma<<<gridLm, 256, 0, stream>>>(A0, A1, A2, WT0, WT1, WT2, b, h, kb0[t], kb1[t]);
      }
    }
  } else if (mode == 1) {
    split_w_kernel<<<(int)(WELEMS / 4 / 256), 256, 0, stream>>>(W, WV0, WV1, WV2);
    gemm_logit_bern<<<gridL32, 256, 0, stream>>>(v_in, W, b, invvar, h, k0a, k0b);
    for (int t = 0; t < NUM_STEPS; ++t) {
      float* vt = out + (size_t)t * B * V;
      gemm_v_mfma<<<gridVm, 256, 0, stream>>>(h, WV0, WV1, WV2, mu, stdv, vt,
                                              nullptr, nullptr, nullptr, kn0[t], kn1[t]);
      if (t < NUM_STEPS - 1) {
        gemm_logit_bern<<<gridL32, 256, 0, stream>>>(vt, W, b, invvar, h, kb0[t], kb1[t]);
      }
    }
  } else {
    gemm_logit_bern<<<gridL32, 256, 0, stream>>>(v_in, W, b, invvar, h, k0a, k0b);
    for (int t = 0; t < NUM_STEPS; ++t) {
      float* vt = out + (size_t)t * B * V;
      gemm_v_sample<<<gridVf, 256, 0, stream>>>(h, W, mu, stdv, vt, kn0[t], kn1[t]);
      if (t < NUM_STEPS - 1) {
        gemm_logit_bern<<<gridL32, 256, 0, stream>>>(vt, W, b, invvar, h, kb0[t], kb1[t]);
      }
    }
  }
}

// Round 11
// 1677.608 us; speedup vs baseline: 1.0647x; 1.0647x over previous
//
#include <hip/hip_runtime.h>
#include <stdint.h>
#include <stddef.h>

// ---------------------------------------------------------------------------
// GRBM Gibbs sampling, round 11. Disentangling R10's regression:
//  - V-mfma: REVERTED to R9-exact (KT=32, 2-barrier, 41KB LDS, 3 blocks/CU).
//    R10's KT=64 cut occupancy 3->2; V's ~40us VALU epilogue needs co-resident
//    waves to hide -> that was the likely regression.
//  - L-mfma: KEEPS 1-barrier dbuf (independent +40% evidence on fp32-L).
// Numerics bit-identical to R9/R10 (same MFMA order) -> absmax must stay
// EXACTLY 0.1015625 (regression canary).
// ---------------------------------------------------------------------------

typedef __attribute__((ext_vector_type(8))) __bf16 bf16x8;
typedef __attribute__((ext_vector_type(4))) float f32x4;

__host__ __device__ inline void threefry2x32(uint32_t k0, uint32_t k1,
                                             uint32_t x0, uint32_t x1,
                                             uint32_t& o0, uint32_t& o1) {
  uint32_t ks2 = k0 ^ k1 ^ 0x1BD11BDAu;
  x0 += k0; x1 += k1;
#define TFR(r) { x0 += x1; x1 = (x1 << (r)) | (x1 >> (32 - (r))); x1 ^= x0; }
  TFR(13) TFR(15) TFR(26) TFR(6)
  x0 += k1;  x1 += ks2 + 1u;
  TFR(17) TFR(29) TFR(16) TFR(24)
  x0 += ks2; x1 += k0 + 2u;
  TFR(13) TFR(15) TFR(26) TFR(6)
  x0 += k0;  x1 += k1 + 3u;
  TFR(17) TFR(29) TFR(16) TFR(24)
  x0 += k1;  x1 += ks2 + 4u;
  TFR(13) TFR(15) TFR(26) TFR(6)
  x0 += ks2; x1 += k0 + 5u;
#undef TFR
  o0 = x0; o1 = x1;
}

__device__ inline float jax_uniform01(uint32_t key0, uint32_t key1, uint32_t idx) {
  uint32_t o0, o1;
  threefry2x32(key0, key1, 0u, idx, o0, o1);
  uint32_t bits = o0 ^ o1;
  return __uint_as_float((bits >> 9) | 0x3f800000u) - 1.0f;
}

__device__ inline float erfinv_xla(float x) {
  float w = -log1pf(-x * x);
  float p;
  if (w < 5.0f) {
    w = w - 2.5f;
    p = 2.81022636e-08f;
    p = fmaf(p, w, 3.43273939e-07f);
    p = fmaf(p, w, -3.5233877e-06f);
    p = fmaf(p, w, -4.39150654e-06f);
    p = fmaf(p, w, 0.00021858087f);
    p = fmaf(p, w, -0.00125372503f);
    p = fmaf(p, w, -0.00417768164f);
    p = fmaf(p, w, 0.246640727f);
    p = fmaf(p, w, 1.50140941f);
  } else {
    w = sqrtf(w) - 3.0f;
    p = -0.000200214257f;
    p = fmaf(p, w, 0.000100950558f);
    p = fmaf(p, w, 0.00134934322f);
    p = fmaf(p, w, -0.00367342844f);
    p = fmaf(p, w, 0.00573950773f);
    p = fmaf(p, w, -0.0076224613f);
    p = fmaf(p, w, 0.00943887047f);
    p = fmaf(p, w, 1.00167406f);
    p = fmaf(p, w, 2.83297682f);
  }
  return p * x;
}

__global__ void prep_kernel(const float* __restrict__ log_var,
                            float* __restrict__ invvar,
                            float* __restrict__ stdv, int V) {
  int i = blockIdx.x * 256 + threadIdx.x;
  if (i < V) {
    float var = fmaxf(expf(log_var[i]), 1e-8f);
    invvar[i] = 1.0f / var;
    stdv[i] = sqrtf(var);
  }
}

__device__ inline unsigned short rtn_bf16(float x, float& back) {
  uint32_t u = __float_as_uint(x);
  uint32_t r = u + 0x7fffu + ((u >> 16) & 1u);
  unsigned short s = (unsigned short)(r >> 16);
  back = __uint_as_float(((uint32_t)s) << 16);
  return s;
}

__device__ inline void split3(float x, unsigned short& s0, unsigned short& s1,
                              unsigned short& s2) {
  float b, r1, r2;
  s0 = rtn_bf16(x, b);  r1 = x - b;
  s1 = rtn_bf16(r1, b); r2 = r1 - b;
  s2 = rtn_bf16(r2, b);
}

__global__ __launch_bounds__(256)
void split_w_kernel(const float* __restrict__ W,
                    unsigned short* __restrict__ P0,
                    unsigned short* __restrict__ P1,
                    unsigned short* __restrict__ P2) {
  int gid = blockIdx.x * 256 + threadIdx.x;
  int base = gid * 4;
  float4 x = *reinterpret_cast<const float4*>(&W[base]);
  ushort4 a0, a1, a2;
  split3(x.x, a0.x, a1.x, a2.x);
  split3(x.y, a0.y, a1.y, a2.y);
  split3(x.z, a0.z, a1.z, a2.z);
  split3(x.w, a0.w, a1.w, a2.w);
  *reinterpret_cast<ushort4*>(&P0[base]) = a0;
  *reinterpret_cast<ushort4*>(&P1[base]) = a1;
  *reinterpret_cast<ushort4*>(&P2[base]) = a2;
}

__global__ __launch_bounds__(256)
void split_wl_kernel(const float* __restrict__ W, const float* __restrict__ invvar,
                     unsigned short* __restrict__ T0,
                     unsigned short* __restrict__ T1,
                     unsigned short* __restrict__ T2) {
  const int N = 512, K = 3072;
  const int n = blockIdx.x * 64 + (threadIdx.x & 63);
  const int kb = blockIdx.y * 16 + (threadIdx.x >> 6) * 4;
  ushort4 a0, a1, a2;
  {
    float w0 = W[(size_t)(kb + 0) * N + n] * invvar[kb + 0];
    float w1 = W[(size_t)(kb + 1) * N + n] * invvar[kb + 1];
    float w2 = W[(size_t)(kb + 2) * N + n] * invvar[kb + 2];
    float w3 = W[(size_t)(kb + 3) * N + n] * invvar[kb + 3];
    split3(w0, a0.x, a1.x, a2.x);
    split3(w1, a0.y, a1.y, a2.y);
    split3(w2, a0.z, a1.z, a2.z);
    split3(w3, a0.w, a1.w, a2.w);
  }
  size_t o = (size_t)n * K + kb;
  *reinterpret_cast<ushort4*>(&T0[o]) = a0;
  *reinterpret_cast<ushort4*>(&T1[o]) = a1;
  *reinterpret_cast<ushort4*>(&T2[o]) = a2;
}

__global__ __launch_bounds__(256)
void split_a_kernel(const float* __restrict__ Vin,
                    unsigned short* __restrict__ A0,
                    unsigned short* __restrict__ A1,
                    unsigned short* __restrict__ A2) {
  int gid = blockIdx.x * 256 + threadIdx.x;
  int base = gid * 4;
  float4 x = *reinterpret_cast<const float4*>(&Vin[base]);
  ushort4 a0, a1, a2;
  split3(x.x, a0.x, a1.x, a2.x);
  split3(x.y, a0.y, a1.y, a2.y);
  split3(x.z, a0.z, a1.z, a2.z);
  split3(x.w, a0.w, a1.w, a2.w);
  *reinterpret_cast<ushort4*>(&A0[base]) = a0;
  *reinterpret_cast<ushort4*>(&A1[base]) = a1;
  *reinterpret_cast<ushort4*>(&A2[base]) = a2;
}

// ---------------------------------------------------------------------------
// Kernel L-MFMA (1-barrier dbuf): logits = v @ (ivv*W) + b ; h = bern(sigmoid).
// M=4096, N=512, K=3072. BM=BN=64, 4 waves (2x2 of 32x32), KT=32.
// 6 pruned passes. grid=512 XCD-swizzled, 2 blocks/CU.
// ---------------------------------------------------------------------------
__global__ __launch_bounds__(256, 1)
void gemm_logit_mfma(const unsigned short* __restrict__ A0,
                     const unsigned short* __restrict__ A1,
                     const unsigned short* __restrict__ A2,
                     const unsigned short* __restrict__ T0,
                     const unsigned short* __restrict__ T1,
                     const unsigned short* __restrict__ T2,
                     const float* __restrict__ bias,
                     uint8_t* __restrict__ Hout, uint32_t kb0, uint32_t kb1) {
  const int N = 512, K = 3072;
  __shared__ __attribute__((aligned(16))) unsigned short As[2][3][64][40];
  __shared__ __attribute__((aligned(16))) unsigned short Bs[2][3][64][40];

  const int tid = threadIdx.x;
  const int bid = blockIdx.x;
  const int xcd = bid & 7;
  const int c = bid >> 3;
  const int mb = xcd * 8 + (c >> 3);     // 0..63
  const int nb = c & 7;                  // 0..7
  const int mBase = mb * 64, nBase = nb * 64;

  const int lane = tid & 63, w = tid >> 6;
  const int wr = w >> 1, wc = w & 1;
  const int lg = lane >> 4, lm = lane & 15;

  const int srow = tid >> 2;        // 0..63
  const int soff = (tid & 3) * 8;   // 0,8,16,24

  f32x4 acc00 = {0.f, 0.f, 0.f, 0.f};
  f32x4 acc01 = {0.f, 0.f, 0.f, 0.f};
  f32x4 acc10 = {0.f, 0.f, 0.f, 0.f};
  f32x4 acc11 = {0.f, 0.f, 0.f, 0.f};

  bf16x8 ra0, ra1, ra2, rb0, rb1, rb2;

#define LOADL(t) { \
  size_t ao = (size_t)(mBase + srow) * K + (t) * 32 + soff; \
  size_t bo = (size_t)(nBase + srow) * K + (t) * 32 + soff; \
  ra0 = *reinterpret_cast<const bf16x8*>(&A0[ao]); \
  ra1 = *reinterpret_cast<const bf16x8*>(&A1[ao]); \
  ra2 = *reinterpret_cast<const bf16x8*>(&A2[ao]); \
  rb0 = *reinterpret_cast<const bf16x8*>(&T0[bo]); \
  rb1 = *reinterpret_cast<const bf16x8*>(&T1[bo]); \
  rb2 = *reinterpret_cast<const bf16x8*>(&T2[bo]); }

#define STAGEL(p) { \
  *reinterpret_cast<bf16x8*>(&As[p][0][srow][soff]) = ra0; \
  *reinterpret_cast<bf16x8*>(&As[p][1][srow][soff]) = ra1; \
  *reinterpret_cast<bf16x8*>(&As[p][2][srow][soff]) = ra2; \
  *reinterpret_cast<bf16x8*>(&Bs[p][0][srow][soff]) = rb0; \
  *reinterpret_cast<bf16x8*>(&Bs[p][1][srow][soff]) = rb1; \
  *reinterpret_cast<bf16x8*>(&Bs[p][2][srow][soff]) = rb2; }

  LOADL(0)

  int p = 0;
  const int NT = K / 32;   // 96
  for (int t = 0; t < NT; ++t) {
    STAGEL(p)
    if (t + 1 < NT) LOADL(t + 1)
    __syncthreads();

    bf16x8 a00 = *reinterpret_cast<const bf16x8*>(&As[p][0][wr * 32 + lm][lg * 8]);
    bf16x8 a01 = *reinterpret_cast<const bf16x8*>(&As[p][0][wr * 32 + 16 + lm][lg * 8]);
    bf16x8 a10 = *reinterpret_cast<const bf16x8*>(&As[p][1][wr * 32 + lm][lg * 8]);
    bf16x8 a11 = *reinterpret_cast<const bf16x8*>(&As[p][1][wr * 32 + 16 + lm][lg * 8]);
    bf16x8 a20 = *reinterpret_cast<const bf16x8*>(&As[p][2][wr * 32 + lm][lg * 8]);
    bf16x8 a21 = *reinterpret_cast<const bf16x8*>(&As[p][2][wr * 32 + 16 + lm][lg * 8]);
    bf16x8 b00 = *reinterpret_cast<const bf16x8*>(&Bs[p][0][wc * 32 + lm][lg * 8]);
    bf16x8 b01 = *reinterpret_cast<const bf16x8*>(&Bs[p][0][wc * 32 + 16 + lm][lg * 8]);
    bf16x8 b10 = *reinterpret_cast<const bf16x8*>(&Bs[p][1][wc * 32 + lm][lg * 8]);
    bf16x8 b11 = *reinterpret_cast<const bf16x8*>(&Bs[p][1][wc * 32 + 16 + lm][lg * 8]);
    bf16x8 b20 = *reinterpret_cast<const bf16x8*>(&Bs[p][2][wc * 32 + lm][lg * 8]);
    bf16x8 b21 = *reinterpret_cast<const bf16x8*>(&Bs[p][2][wc * 32 + 16 + lm][lg * 8]);

#define PASS(aa0, aa1, bb0, bb1) \
    acc00 = __builtin_amdgcn_mfma_f32_16x16x32_bf16(aa0, bb0, acc00, 0, 0, 0); \
    acc01 = __builtin_amdgcn_mfma_f32_16x16x32_bf16(aa0, bb1, acc01, 0, 0, 0); \
    acc10 = __builtin_amdgcn_mfma_f32_16x16x32_bf16(aa1, bb0, acc10, 0, 0, 0); \
    acc11 = __builtin_amdgcn_mfma_f32_16x16x32_bf16(aa1, bb1, acc11, 0, 0, 0);

    PASS(a00, a01, b00, b01)   // A0*B0
    PASS(a00, a01, b10, b11)   // A0*B1
    PASS(a10, a11, b00, b01)   // A1*B0
    PASS(a00, a01, b20, b21)   // A0*B2
    PASS(a10, a11, b10, b11)   // A1*B1
    PASS(a20, a21, b00, b01)   // A2*B0
#undef PASS

    p ^= 1;
  }
#undef LOADL
#undef STAGEL

  const int col0 = nBase + wc * 32 + lm;
  const int col1 = col0 + 16;
  const float bias0 = bias[col0], bias1 = bias[col1];

#define HOUT(accv, r, rowv, colv, bv) { \
  int row = (rowv); int col = (colv); \
  float logit = accv[r] + (bv); \
  float p2 = 0.5f + 0.5f * tanhf(0.5f * logit); \
  uint32_t idx = (uint32_t)row * (uint32_t)N + (uint32_t)col; \
  float u = jax_uniform01(kb0, kb1, idx); \
  Hout[(size_t)row * N + col] = (u < p2) ? (uint8_t)1 : (uint8_t)0; }

#pragma unroll
  for (int r = 0; r < 4; ++r) {
    int row0 = mBase + wr * 32 + lg * 4 + r;
    int row1 = row0 + 16;
    HOUT(acc00, r, row0, col0, bias0)
    HOUT(acc01, r, row0, col1, bias1)
    HOUT(acc10, r, row1, col0, bias0)
    HOUT(acc11, r, row1, col1, bias1)
  }
#undef HOUT
}

// ---------------------------------------------------------------------------
// Kernel V-MFMA (R9-exact: KT=32, 2-barrier dbuf, 41KB LDS, 3 blocks/CU):
// v = h@W^T + mu + nz*std; epilogue also emits the 3-plane bf16 split of v.
// ---------------------------------------------------------------------------
__global__ __launch_bounds__(256, 1)
void gemm_v_mfma(const uint8_t* __restrict__ Hin,
                 const unsigned short* __restrict__ W0,
                 const unsigned short* __restrict__ W1,
                 const unsigned short* __restrict__ W2,
                 const float* __restrict__ muv, const float* __restrict__ stdv,
                 float* __restrict__ Vout,
                 unsigned short* __restrict__ A0,
                 unsigned short* __restrict__ A1,
                 unsigned short* __restrict__ A2,
                 uint32_t kn0, uint32_t kn1) {
  const int N = 3072, K = 512;
  __shared__ __attribute__((aligned(16))) unsigned short As[2][64][40];
  __shared__ __attribute__((aligned(16))) unsigned short Bs[2][3][64][40];

  const int tid = threadIdx.x;
  const int mBase = blockIdx.y * 64, nBase = blockIdx.x * 64;
  const int lane = tid & 63, w = tid >> 6;
  const int wr = w >> 1, wc = w & 1;
  const int lg = lane >> 4, lm = lane & 15;

  const int srow = tid >> 2;
  const int soff = (tid & 3) * 8;

  f32x4 acc00 = {0.f, 0.f, 0.f, 0.f};
  f32x4 acc01 = {0.f, 0.f, 0.f, 0.f};
  f32x4 acc10 = {0.f, 0.f, 0.f, 0.f};
  f32x4 acc11 = {0.f, 0.f, 0.f, 0.f};

  const __bf16 ONE = (__bf16)1.0f;
  const __bf16 ZERO = (__bf16)0.0f;

  uint64_t rh;
  bf16x8 rw0, rw1, rw2;

#define LOADV(t) { \
  int k0 = (t) * 32; \
  rh  = *reinterpret_cast<const uint64_t*>(&Hin[(size_t)(mBase + srow) * K + k0 + soff]); \
  rw0 = *reinterpret_cast<const bf16x8*>(&W0[(size_t)(nBase + srow) * K + k0 + soff]); \
  rw1 = *reinterpret_cast<const bf16x8*>(&W1[(size_t)(nBase + srow) * K + k0 + soff]); \
  rw2 = *reinterpret_cast<const bf16x8*>(&W2[(size_t)(nBase + srow) * K + k0 + soff]); }

#define STAGEV(p) { \
  bf16x8 hv; \
  hv[0] = ((rh >> 0)  & 0xffu) ? ONE : ZERO; \
  hv[1] = ((rh >> 8)  & 0xffu) ? ONE : ZERO; \
  hv[2] = ((rh >> 16) & 0xffu) ? ONE : ZERO; \
  hv[3] = ((rh >> 24) & 0xffu) ? ONE : ZERO; \
  hv[4] = ((rh >> 32) & 0xffu) ? ONE : ZERO; \
  hv[5] = ((rh >> 40) & 0xffu) ? ONE : ZERO; \
  hv[6] = ((rh >> 48) & 0xffu) ? ONE : ZERO; \
  hv[7] = ((rh >> 56) & 0xffu) ? ONE : ZERO; \
  *reinterpret_cast<bf16x8*>(&As[p][srow][soff])    = hv; \
  *reinterpret_cast<bf16x8*>(&Bs[p][0][srow][soff]) = rw0; \
  *reinterpret_cast<bf16x8*>(&Bs[p][1][srow][soff]) = rw1; \
  *reinterpret_cast<bf16x8*>(&Bs[p][2][srow][soff]) = rw2; }

  LOADV(0)
  STAGEV(0)
  __syncthreads();

  int cur = 0;
  const int NT = K / 32;   // 16
  for (int t = 0; t < NT; ++t) {
    const bool more = (t + 1 < NT);
    if (more) LOADV(t + 1)

    bf16x8 a0 = *reinterpret_cast<const bf16x8*>(&As[cur][wr * 32 + lm][lg * 8]);
    bf16x8 a1 = *reinterpret_cast<const bf16x8*>(&As[cur][wr * 32 + 16 + lm][lg * 8]);
    bf16x8 b00 = *reinterpret_cast<const bf16x8*>(&Bs[cur][0][wc * 32 + lm][lg * 8]);
    bf16x8 b01 = *reinterpret_cast<const bf16x8*>(&Bs[cur][0][wc * 32 + 16 + lm][lg * 8]);
    bf16x8 b10 = *reinterpret_cast<const bf16x8*>(&Bs[cur][1][wc * 32 + lm][lg * 8]);
    bf16x8 b11 = *reinterpret_cast<const bf16x8*>(&Bs[cur][1][wc * 32 + 16 + lm][lg * 8]);
    bf16x8 b20 = *reinterpret_cast<const bf16x8*>(&Bs[cur][2][wc * 32 + lm][lg * 8]);
    bf16x8 b21 = *reinterpret_cast<const bf16x8*>(&Bs[cur][2][wc * 32 + 16 + lm][lg * 8]);

    acc00 = __builtin_amdgcn_mfma_f32_16x16x32_bf16(a0, b00, acc00, 0, 0, 0);
    acc01 = __builtin_amdgcn_mfma_f32_16x16x32_bf16(a0, b01, acc01, 0, 0, 0);
    acc10 = __builtin_amdgcn_mfma_f32_16x16x32_bf16(a1, b00, acc10, 0, 0, 0);
    acc11 = __builtin_amdgcn_mfma_f32_16x16x32_bf16(a1, b01, acc11, 0, 0, 0);
    acc00 = __builtin_amdgcn_mfma_f32_16x16x32_bf16(a0, b10, acc00, 0, 0, 0);
    acc01 = __builtin_amdgcn_mfma_f32_16x16x32_bf16(a0, b11, acc01, 0, 0, 0);
    acc10 = __builtin_amdgcn_mfma_f32_16x16x32_bf16(a1, b10, acc10, 0, 0, 0);
    acc11 = __builtin_amdgcn_mfma_f32_16x16x32_bf16(a1, b11, acc11, 0, 0, 0);
    acc00 = __builtin_amdgcn_mfma_f32_16x16x32_bf16(a0, b20, acc00, 0, 0, 0);
    acc01 = __builtin_amdgcn_mfma_f32_16x16x32_bf16(a0, b21, acc01, 0, 0, 0);
    acc10 = __builtin_amdgcn_mfma_f32_16x16x32_bf16(a1, b20, acc10, 0, 0, 0);
    acc11 = __builtin_amdgcn_mfma_f32_16x16x32_bf16(a1, b21, acc11, 0, 0, 0);

    if (more) {
      __syncthreads();
      STAGEV(cur ^ 1)
      __syncthreads();
      cur ^= 1;
    }
  }
#undef LOADV
#undef STAGEV

  const float LO = -0.99999994f;
  const float SQRT2 = 1.41421356237f;
  const int col0 = nBase + wc * 32 + lm;
  const int col1 = col0 + 16;
  const float mu0 = muv[col0], mu1 = muv[col1];
  const float sd0 = stdv[col0], sd1 = stdv[col1];
  const bool emitA = (A0 != nullptr);

#define VOUTM(accv, r, rowv, colv, muvv, sdvv) { \
  int row = (rowv); int col = (colv); \
  float m_v = accv[r] + (muvv); \
  uint32_t idx = (uint32_t)row * (uint32_t)N + (uint32_t)col; \
  float f = jax_uniform01(kn0, kn1, idx); \
  float u = fmaxf(LO, fmaf(f, 2.0f, LO)); \
  float nz = SQRT2 * erfinv_xla(u); \
  float vv = m_v + nz * (sdvv); \
  Vout[(size_t)row * N + col] = vv; \
  if (emitA) { \
    unsigned short s0, s1, s2; \
    split3(vv, s0, s1, s2); \
    size_t ao = (size_t)row * N + col; \
    A0[ao] = s0; A1[ao] = s1; A2[ao] = s2; \
  } }

#pragma unroll
  for (int r = 0; r < 4; ++r) {
    int row0 = mBase + wr * 32 + lg * 4 + r;
    int row1 = row0 + 16;
    VOUTM(acc00, r, row0, col0, mu0, sd0)
    VOUTM(acc01, r, row0, col1, mu1, sd1)
    VOUTM(acc10, r, row1, col0, mu0, sd0)
    VOUTM(acc11, r, row1, col1, mu1, sd1)
  }
#undef VOUTM
}

// ---------------------------------------------------------------------------
// Fallback fp32 kernels (R7-proven) — used when ws_size is too small.
// ---------------------------------------------------------------------------
__global__ __launch_bounds__(256, 1)
void gemm_logit_bern(const float* __restrict__ Vin, const float* __restrict__ Wm,
                     const float* __restrict__ bias, const float* __restrict__ invvar,
                     uint8_t* __restrict__ Hout, uint32_t kb0, uint32_t kb1) {
  const int N = 512, K = 3072;
  const int KT = 32;
  __shared__ float As[2][KT][68];
  __shared__ float Bs[2][KT][64];

  const int tid = threadIdx.x;
  const int bid = blockIdx.x;
  const int xcd = bid & 7;
  const int c = bid >> 3;
  const int mb = xcd * 8 + (c >> 3);
  const int nb = c & 7;
  const int mBase = mb * 64, nBase = nb * 64;

  const int tx = tid & 15, ty = tid >> 4;
  const int am = tid >> 2;
  const int ak = (tid & 3) * 4;
  const int bk = tid >> 4;
  const int bn = (tid & 15) * 4;

  float acc[4][4] = {};
  float4 ra0, ra1, riv0, riv1, rb0, rb1;

#define LOADL(t) { \
  int k0 = (t) * KT; \
  ra0  = *reinterpret_cast<const float4*>(&Vin[(size_t)(mBase + am) * K + k0 + ak]); \
  ra1  = *reinterpret_cast<const float4*>(&Vin[(size_t)(mBase + am) * K + k0 + 16 + ak]); \
  riv0 = *reinterpret_cast<const float4*>(&invvar[k0 + ak]); \
  riv1 = *reinterpret_cast<const float4*>(&invvar[k0 + 16 + ak]); \
  rb0  = *reinterpret_cast<const float4*>(&Wm[(size_t)(k0 + bk) * N + nBase + bn]); \
  rb1  = *reinterpret_cast<const float4*>(&Wm[(size_t)(k0 + 16 + bk) * N + nBase + bn]); }

#define STOREL(p) { \
  As[p][ak + 0][am]      = ra0.x * riv0.x; \
  As[p][ak + 1][am]      = ra0.y * riv0.y; \
  As[p][ak + 2][am]      = ra0.z * riv0.z; \
  As[p][ak + 3][am]      = ra0.w * riv0.w; \
  As[p][ak + 16][am]     = ra1.x * riv1.x; \
  As[p][ak + 17][am]     = ra1.y * riv1.y; \
  As[p][ak + 18][am]     = ra1.z * riv1.z; \
  As[p][ak + 19][am]     = ra1.w * riv1.w; \
  *reinterpret_cast<float4*>(&Bs[p][bk][bn])      = rb0; \
  *reinterpret_cast<float4*>(&Bs[p][bk + 16][bn]) = rb1; }

  LOADL(0)
  int p = 0;
  const int NT = K / KT;
  for (int t = 0; t < NT; ++t) {
    STOREL(p)
    if (t + 1 < NT) LOADL(t + 1)
    __syncthreads();
#pragma unroll
    for (int kk = 0; kk < KT; ++kk) {
      float4 x = *reinterpret_cast<const float4*>(&As[p][kk][ty * 4]);
      float4 y = *reinterpret_cast<const float4*>(&Bs[p][kk][tx * 4]);
#define LROW(i, a) \
      acc[i][0] = fmaf(a, y.x, acc[i][0]); \
      acc[i][1] = fmaf(a, y.y, acc[i][1]); \
      acc[i][2] = fmaf(a, y.z, acc[i][2]); \
      acc[i][3] = fmaf(a, y.w, acc[i][3]);
      LROW(0, x.x) LROW(1, x.y) LROW(2, x.z) LROW(3, x.w)
#undef LROW
    }
    p ^= 1;
  }
#undef LOADL
#undef STOREL

#pragma unroll
  for (int i = 0; i < 4; ++i) {
    int row = mBase + ty * 4 + i;
    uint32_t hp = 0;
#pragma unroll
    for (int j = 0; j < 4; ++j) {
      int col = nBase + tx * 4 + j;
      float logit = acc[i][j] + bias[col];
      float p2 = 0.5f + 0.5f * tanhf(0.5f * logit);
      uint32_t idx = (uint32_t)row * (uint32_t)N + (uint32_t)col;
      float u = jax_uniform01(kb0, kb1, idx);
      hp |= ((u < p2) ? 1u : 0u) << (8 * j);
    }
    *reinterpret_cast<uint32_t*>(&Hout[(size_t)row * N + nBase + tx * 4]) = hp;
  }
}

__global__ __launch_bounds__(256, 2)
void gemm_v_sample(const uint8_t* __restrict__ Hin, const float* __restrict__ Wm,
                   const float* __restrict__ muv, const float* __restrict__ stdv,
                   float* __restrict__ Vout, uint32_t kn0, uint32_t kn1) {
  const int N = 3072, K = 512;
  const int KT = 16;
  __shared__ float As[2][KT][132];
  __shared__ float Bs[2][KT][68];

  const int tid = threadIdx.x;
  const int mBase = blockIdx.y * 128, nBase = blockIdx.x * 64;
  const int tx = tid & 15, ty = tid >> 4;
  const int am = tid >> 1;
  const int ah = (tid & 1) * 8;
  const int bn = tid >> 2;
  const int bq = (tid & 3) * 4;

  float acc[8][4] = {};
  uint32_t rh0, rh1;
  float4 rb;
  {
    const uint32_t* hp_ = reinterpret_cast<const uint32_t*>(&Hin[(size_t)(mBase + am) * K + ah]);
    rh0 = hp_[0]; rh1 = hp_[1];
  }
  rb = *reinterpret_cast<const float4*>(&Wm[(size_t)(nBase + bn) * K + bq]);

#define STAGE_V(buf) { \
  As[buf][ah + 0][am] = (float)((rh0 >> 0) & 0xffu); \
  As[buf][ah + 1][am] = (float)((rh0 >> 8) & 0xffu); \
  As[buf][ah + 2][am] = (float)((rh0 >> 16) & 0xffu); \
  As[buf][ah + 3][am] = (float)((rh0 >> 24) & 0xffu); \
  As[buf][ah + 4][am] = (float)((rh1 >> 0) & 0xffu); \
  As[buf][ah + 5][am] = (float)((rh1 >> 8) & 0xffu); \
  As[buf][ah + 6][am] = (float)((rh1 >> 16) & 0xffu); \
  As[buf][ah + 7][am] = (float)((rh1 >> 24) & 0xffu); \
  Bs[buf][bq + 0][bn] = rb.x; \
  Bs[buf][bq + 1][bn] = rb.y; \
  Bs[buf][bq + 2][bn] = rb.z; \
  Bs[buf][bq + 3][bn] = rb.w; }

  STAGE_V(0)
  __syncthreads();

  int cur = 0;
  const int NT = K / KT;
  for (int t = 0; t < NT; ++t) {
    const bool more = (t + 1 < NT);
    if (more) {
      int k0 = (t + 1) * KT;
      const uint32_t* hp_ = reinterpret_cast<const uint32_t*>(&Hin[(size_t)(mBase + am) * K + k0 + ah]);
      rh0 = hp_[0]; rh1 = hp_[1];
      rb = *reinterpret_cast<const float4*>(&Wm[(size_t)(nBase + bn) * K + k0 + bq]);
    }
#pragma unroll
    for (int kk = 0; kk < KT; ++kk) {
      float4 x0 = *reinterpret_cast<const float4*>(&As[cur][kk][ty * 8]);
      float4 x1 = *reinterpret_cast<const float4*>(&As[cur][kk][ty * 8 + 4]);
      float4 y  = *reinterpret_cast<const float4*>(&Bs[cur][kk][tx * 4]);
#define VROW(i, a) \
      acc[i][0] = fmaf(a, y.x, acc[i][0]); \
      acc[i][1] = fmaf(a, y.y, acc[i][1]); \
      acc[i][2] = fmaf(a, y.z, acc[i][2]); \
      acc[i][3] = fmaf(a, y.w, acc[i][3]);
      VROW(0, x0.x) VROW(1, x0.y) VROW(2, x0.z) VROW(3, x0.w)
      VROW(4, x1.x) VROW(5, x1.y) VROW(6, x1.z) VROW(7, x1.w)
#undef VROW
    }
    if (more) {
      __syncthreads();
      STAGE_V(cur ^ 1)
      __syncthreads();
      cur ^= 1;
    }
  }
#undef STAGE_V

  const float LO = -0.99999994f;
  const float SQRT2 = 1.41421356237f;
  const float4 mu4 = *reinterpret_cast<const float4*>(&muv[nBase + tx * 4]);
  const float4 sd4 = *reinterpret_cast<const float4*>(&stdv[nBase + tx * 4]);
  const float mur[4] = {mu4.x, mu4.y, mu4.z, mu4.w};
  const float sdr[4] = {sd4.x, sd4.y, sd4.z, sd4.w};
#pragma unroll
  for (int i = 0; i < 8; ++i) {
    int row = mBase + ty * 8 + i;
    float o0, o1, o2, o3;
#define VOUT(j, dst) { \
      int col = nBase + tx * 4 + j; \
      float m_v = acc[i][j] + mur[j]; \
      uint32_t idx = (uint32_t)row * (uint32_t)N + (uint32_t)col; \
      float f = jax_uniform01(kn0, kn1, idx); \
      float u = fmaxf(LO, fmaf(f, 2.0f, LO)); \
      float nz = SQRT2 * erfinv_xla(u); \
      dst = m_v + nz * sdr[j]; }
    VOUT(0, o0) VOUT(1, o1) VOUT(2, o2) VOUT(3, o3)
#undef VOUT
    float4 s = {o0, o1, o2, o3};
    *reinterpret_cast<float4*>(&Vout[(size_t)row * N + nBase + tx * 4]) = s;
  }
}

extern "C" void kernel_launch(void* const* d_in, const int* in_sizes, int n_in,
                              void* d_out, int out_size, void* d_ws, size_t ws_size,
                              hipStream_t stream) {
  const int B = 4096, V = 3072, H = 512, NUM_STEPS = 8;
  const float* v_in    = (const float*)d_in[0];
  const float* W       = (const float*)d_in[1];
  const float* b       = (const float*)d_in[2];
  const float* mu      = (const float*)d_in[3];
  const float* log_var = (const float*)d_in[4];
  float* out = (float*)d_out;

  const size_t WELEMS = (size_t)V * H;           // 1,572,864
  const size_t AELEMS = (size_t)B * V;           // 12,582,912
  const size_t NEED_FULL = 24576 + 6 * WELEMS * 2 + 3 * AELEMS * 2 + (size_t)B * H;
  const size_t NEED_MID  = 24576 + 3 * WELEMS * 2 + (size_t)B * H;
  const int mode = (ws_size >= NEED_FULL) ? 2 : (ws_size >= NEED_MID) ? 1 : 0;

  float* invvar = (float*)d_ws;
  float* stdv   = invvar + V;
  unsigned short* WV0 = (unsigned short*)(stdv + V);
  unsigned short* WV1 = WV0 + WELEMS;
  unsigned short* WV2 = WV1 + WELEMS;
  unsigned short* WT0 = WV2 + WELEMS;
  unsigned short* WT1 = WT0 + WELEMS;
  unsigned short* WT2 = WT1 + WELEMS;
  unsigned short* A0  = WT2 + WELEMS;
  unsigned short* A1  = A0 + AELEMS;
  unsigned short* A2  = A1 + AELEMS;
  uint8_t* h;
  if (mode == 2)      h = (uint8_t*)(A2 + AELEMS);
  else if (mode == 1) h = (uint8_t*)(WV2 + WELEMS);
  else                h = (uint8_t*)(stdv + V);

  uint32_t k0a, k0b, kl0, kl1;
  threefry2x32(0u, 42u, 0u, 0u, k0a, k0b);
  threefry2x32(0u, 42u, 0u, 1u, kl0, kl1);
  uint32_t kn0[NUM_STEPS], kn1[NUM_STEPS], kb0[NUM_STEPS], kb1[NUM_STEPS];
  for (int t = 0; t < NUM_STEPS; ++t) {
    uint32_t kt0, kt1;
    threefry2x32(kl0, kl1, 0u, (uint32_t)t, kt0, kt1);
    threefry2x32(kt0, kt1, 0u, 0u, kn0[t], kn1[t]);
    threefry2x32(kt0, kt1, 0u, 1u, kb0[t], kb1[t]);
  }

  prep_kernel<<<(V + 255) / 256, 256, 0, stream>>>(log_var, invvar, stdv, V);

  dim3 gridL32(512);
  dim3 gridLm(512);
  dim3 gridVm(V / 64, B / 64);     // (48, 64)
  dim3 gridVf(V / 64, B / 128);

  if (mode == 2) {
    split_w_kernel<<<(int)(WELEMS / 4 / 256), 256, 0, stream>>>(W, WV0, WV1, WV2);
    split_wl_kernel<<<dim3(H / 64, V / 16), 256, 0, stream>>>(W, invvar, WT0, WT1, WT2);
    split_a_kernel<<<(int)(AELEMS / 4 / 256), 256, 0, stream>>>(v_in, A0, A1, A2);

    gemm_logit_mfma<<<gridLm, 256, 0, stream>>>(A0, A1, A2, WT0, WT1, WT2, b, h, k0a, k0b);
    for (int t = 0; t < NUM_STEPS; ++t) {
      float* vt = out + (size_t)t * B * V;
      gemm_v_mfma<<<gridVm, 256, 0, stream>>>(h, WV0, WV1, WV2, mu, stdv, vt,
                                              A0, A1, A2, kn0[t], kn1[t]);
      if (t < NUM_STEPS - 1) {
        gemm_logit_mfma<<<gridLm, 256, 0, stream>>>(A0, A1, A2, WT0, WT1, WT2, b, h, kb0[t], kb1[t]);
      }
    }
  } else if (mode == 1) {
    split_w_kernel<<<(int)(WELEMS / 4 / 256), 256, 0, stream>>>(W, WV0, WV1, WV2);
    gemm_logit_bern<<<gridL32, 256, 0, stream>>>(v_in, W, b, invvar, h, k0a, k0b);
    for (int t = 0; t < NUM_STEPS; ++t) {
      float* vt = out + (size_t)t * B * V;
      gemm_v_mfma<<<gridVm, 256, 0, stream>>>(h, WV0, WV1, WV2, mu, stdv, vt,
                                              nullptr, nullptr, nullptr, kn0[t], kn1[t]);
      if (t < NUM_STEPS - 1) {
        gemm_logit_bern<<<gridL32, 256, 0, stream>>>(vt, W, b, invvar, h, kb0[t], kb1[t]);
      }
    }
  } else {
    gemm_logit_bern<<<gridL32, 256, 0, stream>>>(v_in, W, b, invvar, h, k0a, k0b);
    for (int t = 0; t < NUM_STEPS; ++t) {
      float* vt = out + (size_t)t * B * V;
      gemm_v_sample<<<gridVf, 256, 0, stream>>>(h, W, mu, stdv, vt, kn0[t], kn1[t]);
      if (t < NUM_STEPS - 1) {
        gemm_logit_bern<<<gridL32, 256, 0, stream>>>(vt, W, b, invvar, h, kb0[t], kb1[t]);
      }
    }
  }
}